// Round 4
// baseline (1459.078 us; speedup 1.0000x reference)
//
#include <hip/hip_runtime.h>

#define NPOIS 100000
#define NHYP  50000
#define NNZE  1600000
#define DIM   256

typedef unsigned int uint;

// exact f32 value of the reference's dropout scale 1/(1-0.3)
#define DROP_C ((float)(1.0 / (1.0 - 0.3)))

// ---------- bf16 helpers (RNE) ----------
__device__ __forceinline__ uint pack_bf16(float a, float b) {
    uint ua = __float_as_uint(a); ua += 0x7fffu + ((ua >> 16) & 1u);
    uint ub = __float_as_uint(b); ub += 0x7fffu + ((ub >> 16) & 1u);
    return (ua >> 16) | (ub & 0xffff0000u);
}
__device__ __forceinline__ float2 unpack2(uint u) {
    return make_float2(__uint_as_float(u << 16), __uint_as_float(u & 0xffff0000u));
}

// f32 [n4 float4] -> bf16 [n4 uint2]
__global__ __launch_bounds__(256) void to_h_kernel(
    const float4* __restrict__ in, uint2* __restrict__ out, int n4)
{
    int stride = gridDim.x * blockDim.x;
    for (int i = blockIdx.x * blockDim.x + threadIdx.x; i < n4; i += stride) {
        float4 x = in[i];
        out[i] = make_uint2(pack_bf16(x.x, x.y), pack_bf16(x.z, x.w));
    }
}

// drop masks (values in {0, DROP_C}) -> 1 bit per element.
// word w covers elements [32w, 32w+32) of the flattened (L, NPOIS, DIM)
// array; bit j <-> element 32w+j. (verified correct in round 1)
__global__ __launch_bounds__(256) void drop_bits_kernel(
    const float4* __restrict__ d1, const float4* __restrict__ d2,
    uint* __restrict__ o1, uint* __restrict__ o2, int nw)
{
    int t = blockIdx.x * blockDim.x + threadIdx.x;
    if (t >= 2 * nw) return;
    const float4* src = (t < nw) ? d1 : d2;
    uint* dst = (t < nw) ? o1 : o2;
    int w = (t < nw) ? t : t - nw;
    uint m = 0;
#pragma unroll
    for (int q = 0; q < 8; ++q) {
        float4 v = src[(size_t)w * 8 + q];
        m |= (v.x != 0.f ? 1u : 0u) << (4 * q);
        m |= (v.y != 0.f ? 2u : 0u) << (4 * q);
        m |= (v.z != 0.f ? 4u : 0u) << (4 * q);
        m |= (v.w != 0.f ? 8u : 0u) << (4 * q);
    }
    dst[w] = m;
}

// ---------- CSR build ----------
__global__ __launch_bounds__(256) void hist_kernel(
    const int* __restrict__ tr, const int* __restrict__ sr,
    int* __restrict__ cnt_tar, int* __restrict__ cnt_src, int nnz)
{
    int e = blockIdx.x * blockDim.x + threadIdx.x;
    if (e >= nnz) return;
    atomicAdd(&cnt_tar[tr[e]], 1);
    atomicAdd(&cnt_src[sr[e]], 1);
}

#define SCAN_TILE 1024

__global__ __launch_bounds__(256) void scan_part(
    const int* __restrict__ in, int* __restrict__ out, int* __restrict__ bsums, int n)
{
    __shared__ int lds[256];
    int t = threadIdx.x;
    int base = blockIdx.x * SCAN_TILE + t * 4;
    int v[4];
#pragma unroll
    for (int j = 0; j < 4; ++j) v[j] = (base + j < n) ? in[base + j] : 0;
    int s = v[0] + v[1] + v[2] + v[3];
    lds[t] = s;
    __syncthreads();
    for (int off = 1; off < 256; off <<= 1) {
        int x = (t >= off) ? lds[t - off] : 0;
        __syncthreads();
        lds[t] += x;
        __syncthreads();
    }
    int run = lds[t] - s;
#pragma unroll
    for (int j = 0; j < 4; ++j) {
        if (base + j < n) out[base + j] = run;
        run += v[j];
    }
    if (t == 255) bsums[blockIdx.x] = lds[255];
}

__global__ __launch_bounds__(256) void scan_sums(int* __restrict__ bsums, int nb)
{
    __shared__ int lds[256];
    int t = threadIdx.x;
    int v = (t < nb) ? bsums[t] : 0;
    lds[t] = v;
    __syncthreads();
    for (int off = 1; off < 256; off <<= 1) {
        int x = (t >= off) ? lds[t - off] : 0;
        __syncthreads();
        lds[t] += x;
        __syncthreads();
    }
    if (t < nb) bsums[t] = lds[t] - v;
}

__global__ __launch_bounds__(256) void add_off(
    int* __restrict__ rp, const int* __restrict__ bsums, int n, int total)
{
    int i = blockIdx.x * blockDim.x + threadIdx.x;
    if (i < n) rp[i] += bsums[i >> 10];
    if (i == 0) rp[n] = total;
}

// permute (col,val) into packed CSR order; pack edge record into 4 B:
// u = (col << 15) | (bf16(val) & 0x7fff).  col < 2^17; val in [0,1) =>
// sign=0, so bf16's low 15 bits (exp8|man7) reconstruct exactly via
// (u & 0x7fff) << 16.
__global__ __launch_bounds__(256) void bucket_packed(
    const int* __restrict__ rows, const int* __restrict__ cols,
    const float* __restrict__ vals, const int* __restrict__ rp,
    int* __restrict__ cnt, uint* __restrict__ ep, int nnz)
{
    int e = blockIdx.x * blockDim.x + threadIdx.x;
    if (e >= nnz) return;
    int r = rows[e];
    int slot = rp[r] + atomicAdd(&cnt[r], 1);
    uint uv = __float_as_uint(vals[e]);
    uv += 0x7fffu + ((uv >> 16) & 1u);          // RNE to bf16
    ep[slot] = ((uint)cols[e] << 15) | ((uv >> 16) & 0x7fffu);
}

// ---------- half-D gather cores ----------
// One wave = (row, dim-half): halves the per-phase gather working set.
// row is wave-uniform (readfirstlane) -> ep loads are scalar broadcasts.
__device__ __forceinline__ float2 gather_h_half(
    const int* __restrict__ rp, const uint* __restrict__ ep,
    const uint* __restrict__ dh, int row, int hf, int lane)
{
    int s = rp[row], e = rp[row + 1];
    float2 acc = {0.f, 0.f};
#pragma unroll 8
    for (int k = s; k < e; ++k) {
        uint u = ep[k];                                   // uniform -> s_load
        float vv = __uint_as_float((u & 0x7fffu) << 16);  // bf16 val (sign=0)
        uint x = dh[(size_t)(u >> 15) * (DIM / 2) + hf * 64 + lane];
        acc.x += vv * __uint_as_float(x << 16);
        acc.y += vv * __uint_as_float(x & 0xffff0000u);
    }
    return acc;
}

__device__ __forceinline__ float2 gather_f_half(
    const int* __restrict__ rp, const uint* __restrict__ ep,
    const float2* __restrict__ dv, int row, int hf, int lane)
{
    int s = rp[row], e = rp[row + 1];
    float2 acc = {0.f, 0.f};
#pragma unroll 8
    for (int k = s; k < e; ++k) {
        uint u = ep[k];
        float vv = __uint_as_float((u & 0x7fffu) << 16);
        float2 x = dv[(size_t)(u >> 15) * (DIM / 2) + hf * 64 + lane];
        acc.x += vv * x.x;
        acc.y += vv * x.y;
    }
    return acc;
}

// hyperedge-side SpMM -> bf16 out, half-D. BF16D: dense is bf16.
template <bool BF16D>
__global__ __launch_bounds__(256) void spmm_to_h_half(
    const int* __restrict__ rp, const uint* __restrict__ ep,
    const void* __restrict__ dense, uint* __restrict__ out_h, int nrows)
{
    int wid  = (blockIdx.x * blockDim.x + threadIdx.x) >> 6;
    int lane = threadIdx.x & 63;
    if (wid >= 2 * nrows) return;
    int hw  = (wid >= nrows) ? 1 : 0;
    int row = __builtin_amdgcn_readfirstlane(wid - hw * nrows);
    int hf  = __builtin_amdgcn_readfirstlane(hw);
    float2 a = BF16D ? gather_h_half(rp, ep, (const uint*)dense, row, hf, lane)
                     : gather_f_half(rp, ep, (const float2*)dense, row, hf, lane);
    out_h[(size_t)row * (DIM / 2) + hf * 64 + lane] = pack_bf16(a.x, a.y);
}

// poi-side SpMM + layer-1 epilogue -> embs1 (bf16), half-D.
template <bool PH, bool BITS>
__global__ __launch_bounds__(256) void spmm_epi1_half(
    const int* __restrict__ rp, const uint* __restrict__ ep,
    const uint* __restrict__ msg_h,
    const uint* __restrict__ pois_h, const float2* __restrict__ pois_f,
    const float2* __restrict__ d1f, const float2* __restrict__ d2f,
    const uint* __restrict__ bm1, const uint* __restrict__ bm2,
    uint* __restrict__ out_h, int nrows)
{
    int wid  = (blockIdx.x * blockDim.x + threadIdx.x) >> 6;
    int lane = threadIdx.x & 63;
    if (wid >= 2 * nrows) return;
    int hw  = (wid >= nrows) ? 1 : 0;
    int row = __builtin_amdgcn_readfirstlane(wid - hw * nrows);
    int hf  = __builtin_amdgcn_readfirstlane(hw);

    size_t idx = (size_t)row * (DIM / 2) + hf * 64 + lane;
    // independent stream loads issued before the gather loop
    float2 p = PH ? unpack2(pois_h[idx]) : pois_f[idx];
    float a0, a1, b0, b1;
    if (BITS) {
        size_t widx = (size_t)row * 8 + hf * 4 + (lane >> 4);
        uint sh = (lane & 15) * 2;
        uint m1 = bm1[widx] >> sh;
        uint m2 = bm2[widx] >> sh;
        a0 = (m1 & 1u) ? DROP_C : 0.f;  a1 = (m1 & 2u) ? DROP_C : 0.f;
        b0 = (m2 & 1u) ? DROP_C : 0.f;  b1 = (m2 & 2u) ? DROP_C : 0.f;
    } else {
        float2 av = d1f[idx]; a0 = av.x; a1 = av.y;
        float2 bv = d2f[idx]; b0 = bv.x; b1 = bv.y;
    }
    float2 m = gather_h_half(rp, ep, msg_h, row, hf, lane);
    float r0 = (fmaxf(m.x, 0.f) * a0 + p.x) * b0;
    float r1 = (fmaxf(m.y, 0.f) * a1 + p.y) * b1;
    out_h[idx] = pack_bf16(r0, r1);
}

// poi-side SpMM + layer-2 epilogue + softmax combine -> f32 out, half-D.
template <bool PH, bool BITS>
__global__ __launch_bounds__(256) void spmm_final_half(
    const int* __restrict__ rp, const uint* __restrict__ ep,
    const uint* __restrict__ msg_h,
    const uint* __restrict__ pois_h, const float2* __restrict__ pois_f,
    const uint* __restrict__ embs1_h,
    const float2* __restrict__ d1f, const float2* __restrict__ d2f,
    const uint* __restrict__ bm1, const uint* __restrict__ bm2,
    const float* __restrict__ attn, float2* __restrict__ out, int nrows)
{
    int wid  = (blockIdx.x * blockDim.x + threadIdx.x) >> 6;
    int lane = threadIdx.x & 63;
    if (wid >= 2 * nrows) return;
    int hw  = (wid >= nrows) ? 1 : 0;
    int row = __builtin_amdgcn_readfirstlane(wid - hw * nrows);
    int hf  = __builtin_amdgcn_readfirstlane(hw);

    float t0 = attn[0], t1 = attn[1], t2 = attn[2];
    float mx = fmaxf(t0, fmaxf(t1, t2));
    float e0 = __expf(t0 - mx), e1 = __expf(t1 - mx), e2 = __expf(t2 - mx);
    float inv = 1.f / (e0 + e1 + e2);
    float w0 = e0 * inv, w1 = e1 * inv, w2 = e2 * inv;

    size_t idx = (size_t)row * (DIM / 2) + hf * 64 + lane;
    float2 p0 = PH ? unpack2(pois_h[idx]) : pois_f[idx];
    float2 p1 = unpack2(embs1_h[idx]);
    float a0, a1, b0, b1;
    if (BITS) {
        size_t widx = (size_t)row * 8 + hf * 4 + (lane >> 4);
        uint sh = (lane & 15) * 2;
        uint m1 = bm1[widx] >> sh;
        uint m2 = bm2[widx] >> sh;
        a0 = (m1 & 1u) ? DROP_C : 0.f;  a1 = (m1 & 2u) ? DROP_C : 0.f;
        b0 = (m2 & 1u) ? DROP_C : 0.f;  b1 = (m2 & 2u) ? DROP_C : 0.f;
    } else {
        float2 av = d1f[idx]; a0 = av.x; a1 = av.y;
        float2 bv = d2f[idx]; b0 = bv.x; b1 = bv.y;
    }
    float2 m = gather_h_half(rp, ep, msg_h, row, hf, lane);
    float r0 = w0 * p0.x + w1 * p1.x + w2 * ((fmaxf(m.x, 0.f) * a0 + p1.x) * b0);
    float r1 = w0 * p0.y + w1 * p1.y + w2 * ((fmaxf(m.y, 0.f) * a1 + p1.y) * b1);
    out[idx] = make_float2(r0, r1);
}

// ---------- launch ----------
extern "C" void kernel_launch(void* const* d_in, const int* in_sizes, int n_in,
                              void* d_out, int out_size, void* d_ws, size_t ws_size,
                              hipStream_t stream)
{
    const float* pois     = (const float*)d_in[0];
    const float* tar_vals = (const float*)d_in[1];
    const float* src_vals = (const float*)d_in[2];
    const float* attn     = (const float*)d_in[3];
    const float* drop1    = (const float*)d_in[4];
    const float* drop2    = (const float*)d_in[5];
    const int*   tar_rows = (const int*)d_in[6];
    const int*   tar_cols = (const int*)d_in[7];
    const int*   src_rows = (const int*)d_in[8];
    const int*   src_cols = (const int*)d_in[9];

    const size_t ptn = (size_t)NPOIS * DIM;

    // workspace layout (bytes, 16B-aligned chunks).
    // Packed 4-B edges free exactly the 12.8 MB the bitmasks need:
    // total = 154.2 MB, identical to the round-0 layout that fit.
    char* p = (char*)d_ws;
    uint* ep_tar   = (uint*)p;              p += (size_t)NNZE * 4;            // 6.4 MB
    uint* ep_src   = (uint*)p;              p += (size_t)NNZE * 4;            // 6.4 MB
    int*  rp_tar   = (int*)p;               p += 200064;                      // NHYP+1
    int*  rp_src   = (int*)p;               p += 400064;                      // NPOIS+1
    uint* msg_h    = (uint*)p;              p += (size_t)NHYP * DIM * 2;      // 25.6 MB
    uint* embs1_h  = (uint*)p;              p += (size_t)NPOIS * DIM * 2;     // 51.2 MB

    const size_t bits_words = (size_t)2 * NPOIS * 8;   // per array (2 layers)
    uint* bits1 = (uint*)p;
    uint* bits2 = bits1 + bits_words;       p += 2 * bits_words * 4;          // 12.8 MB
    size_t bits_need = (size_t)(p - (char*)d_ws);
    bool have_bits = ws_size >= bits_need;

    uint* pois_h = (uint*)p;                                                  // +51.2 MB
    bool full = ws_size >= bits_need + ptn * 2;

    // cnt/bsums scratch overlaid in msg_h (unused during CSR build)
    int* cnt_tar = (int*)msg_h;
    int* cnt_src = cnt_tar + NHYP;
    int* bsums   = cnt_src + NPOIS;

    const int BLK = 256;
    const int nnz_blocks = (NNZE + BLK - 1) / BLK;

    // optional f32->bf16 pois copy
    if (full)
        to_h_kernel<<<(int)(ptn / 4 + BLK - 1) / BLK, BLK, 0, stream>>>(
            (const float4*)pois, (uint2*)pois_h, (int)(ptn / 4));

    // drop masks -> bits (both layers of both arrays in one pass)
    if (have_bits) {
        int nw = (int)(2 * ptn / 32);   // words per array
        drop_bits_kernel<<<(2 * nw + BLK - 1) / BLK, BLK, 0, stream>>>(
            (const float4*)drop1, (const float4*)drop2, bits1, bits2, nw);
    }

    // ---- CSR build ----
    hipMemsetAsync(cnt_tar, 0, (size_t)(NHYP + NPOIS) * sizeof(int), stream);
    hist_kernel<<<nnz_blocks, BLK, 0, stream>>>(tar_rows, src_rows, cnt_tar, cnt_src, NNZE);

    int tb_tar = (NHYP + SCAN_TILE - 1) / SCAN_TILE;
    scan_part<<<tb_tar, BLK, 0, stream>>>(cnt_tar, rp_tar, bsums, NHYP);
    scan_sums<<<1, BLK, 0, stream>>>(bsums, tb_tar);
    add_off<<<(NHYP + BLK - 1) / BLK, BLK, 0, stream>>>(rp_tar, bsums, NHYP, NNZE);

    int tb_src = (NPOIS + SCAN_TILE - 1) / SCAN_TILE;
    scan_part<<<tb_src, BLK, 0, stream>>>(cnt_src, rp_src, bsums, NPOIS);
    scan_sums<<<1, BLK, 0, stream>>>(bsums, tb_src);
    add_off<<<(NPOIS + BLK - 1) / BLK, BLK, 0, stream>>>(rp_src, bsums, NPOIS, NNZE);

    hipMemsetAsync(cnt_tar, 0, (size_t)(NHYP + NPOIS) * sizeof(int), stream);
    bucket_packed<<<nnz_blocks, BLK, 0, stream>>>(tar_rows, tar_cols, tar_vals, rp_tar, cnt_tar, ep_tar, NNZE);
    bucket_packed<<<nnz_blocks, BLK, 0, stream>>>(src_rows, src_cols, src_vals, rp_src, cnt_src, ep_src, NNZE);

    // 2*nrows waves (halves time-separated), 4 waves/block
    const int gb_hyp2 = NHYP / 2;    // 25000 blocks
    const int gb_poi2 = NPOIS / 2;   // 50000 blocks

    const float2* d1f_l0 = (const float2*)drop1;
    const float2* d2f_l0 = (const float2*)drop2;
    const float2* d1f_l1 = (const float2*)(drop1 + ptn);
    const float2* d2f_l1 = (const float2*)(drop2 + ptn);
    const uint* b1_l0 = bits1;
    const uint* b2_l0 = bits2;
    const uint* b1_l1 = bits1 + (size_t)NPOIS * 8;
    const uint* b2_l1 = bits2 + (size_t)NPOIS * 8;

    // ---- layer 1 ----
    if (full)
        spmm_to_h_half<true><<<gb_hyp2, BLK, 0, stream>>>(rp_tar, ep_tar, pois_h, msg_h, NHYP);
    else
        spmm_to_h_half<false><<<gb_hyp2, BLK, 0, stream>>>(rp_tar, ep_tar, pois, msg_h, NHYP);

    if (full && have_bits)
        spmm_epi1_half<true, true><<<gb_poi2, BLK, 0, stream>>>(
            rp_src, ep_src, msg_h, pois_h, (const float2*)pois,
            d1f_l0, d2f_l0, b1_l0, b2_l0, embs1_h, NPOIS);
    else if (full)
        spmm_epi1_half<true, false><<<gb_poi2, BLK, 0, stream>>>(
            rp_src, ep_src, msg_h, pois_h, (const float2*)pois,
            d1f_l0, d2f_l0, b1_l0, b2_l0, embs1_h, NPOIS);
    else if (have_bits)
        spmm_epi1_half<false, true><<<gb_poi2, BLK, 0, stream>>>(
            rp_src, ep_src, msg_h, pois_h, (const float2*)pois,
            d1f_l0, d2f_l0, b1_l0, b2_l0, embs1_h, NPOIS);
    else
        spmm_epi1_half<false, false><<<gb_poi2, BLK, 0, stream>>>(
            rp_src, ep_src, msg_h, pois_h, (const float2*)pois,
            d1f_l0, d2f_l0, b1_l0, b2_l0, embs1_h, NPOIS);

    // ---- layer 2 ----
    spmm_to_h_half<true><<<gb_hyp2, BLK, 0, stream>>>(rp_tar, ep_tar, embs1_h, msg_h, NHYP);

    if (full && have_bits)
        spmm_final_half<true, true><<<gb_poi2, BLK, 0, stream>>>(
            rp_src, ep_src, msg_h, pois_h, (const float2*)pois, embs1_h,
            d1f_l1, d2f_l1, b1_l1, b2_l1, attn, (float2*)d_out, NPOIS);
    else if (full)
        spmm_final_half<true, false><<<gb_poi2, BLK, 0, stream>>>(
            rp_src, ep_src, msg_h, pois_h, (const float2*)pois, embs1_h,
            d1f_l1, d2f_l1, b1_l1, b2_l1, attn, (float2*)d_out, NPOIS);
    else if (have_bits)
        spmm_final_half<false, true><<<gb_poi2, BLK, 0, stream>>>(
            rp_src, ep_src, msg_h, pois_h, (const float2*)pois, embs1_h,
            d1f_l1, d2f_l1, b1_l1, b2_l1, attn, (float2*)d_out, NPOIS);
    else
        spmm_final_half<false, false><<<gb_poi2, BLK, 0, stream>>>(
            rp_src, ep_src, msg_h, pois_h, (const float2*)pois, embs1_h,
            d1f_l1, d2f_l1, b1_l1, b2_l1, attn, (float2*)d_out, NPOIS);
}

// Round 5
// 1186.620 us; speedup vs baseline: 1.2296x; 1.2296x over previous
//
#include <hip/hip_runtime.h>

#define NPOIS 100000
#define NHYP  50000
#define NNZE  1600000
#define DIM   256

// coarse bucket shifts: 782 buckets for both matrices
#define SH_TAR 6    // 64 rows/bucket, ceil(50000/64)  = 782
#define SH_SRC 7    // 128 rows/bucket, ceil(100000/128) = 782
#define NBUCK 782
#define CHUNK 6250  // 256 blocks * 6250 = 1,600,000 = NNZE exactly

typedef unsigned int uint;

// ---------- bf16 helpers (RNE) ----------
__device__ __forceinline__ uint pack_bf16(float a, float b) {
    uint ua = __float_as_uint(a); ua += 0x7fffu + ((ua >> 16) & 1u);
    uint ub = __float_as_uint(b); ub += 0x7fffu + ((ub >> 16) & 1u);
    return (ua >> 16) | (ub & 0xffff0000u);
}
__device__ __forceinline__ float4 unpack_h(uint2 u) {
    return make_float4(__uint_as_float(u.x << 16), __uint_as_float(u.x & 0xffff0000u),
                       __uint_as_float(u.y << 16), __uint_as_float(u.y & 0xffff0000u));
}

// f32 [n4 float4] -> bf16 [n4 uint2]
__global__ __launch_bounds__(256) void to_h_kernel(
    const float4* __restrict__ in, uint2* __restrict__ out, int n4)
{
    int stride = gridDim.x * blockDim.x;
    for (int i = blockIdx.x * blockDim.x + threadIdx.x; i < n4; i += stride) {
        float4 x = in[i];
        out[i] = make_uint2(pack_bf16(x.x, x.y), pack_bf16(x.z, x.w));
    }
}

// ---------- CSR build v2: two-level bucket sort ----------
// Replaces the random 8-B scatter (bucket_packed: ~1.6M L2-line RMWs) and
// the 3.2M-atomics-on-25-lines histogram with LDS-aggregated passes whose
// global writes land in contiguous per-bucket extents.

// coarse histogram, LDS-aggregated (both matrices in one pass)
__global__ __launch_bounds__(256) void hist_coarse(
    const int* __restrict__ tr, const int* __restrict__ sr,
    int* __restrict__ c_tar, int* __restrict__ c_src, int nnz)
{
    __shared__ int lt[NBUCK], ls[NBUCK];
    int t = threadIdx.x;
    int s = blockIdx.x * CHUNK, e = min(s + CHUNK, nnz);
    for (int i = t; i < NBUCK; i += 256) { lt[i] = 0; ls[i] = 0; }
    __syncthreads();
    for (int i = s + t; i < e; i += 256) {
        atomicAdd(&lt[tr[i] >> SH_TAR], 1);
        atomicAdd(&ls[sr[i] >> SH_SRC], 1);
    }
    __syncthreads();
    for (int i = t; i < NBUCK; i += 256) {
        if (lt[i]) atomicAdd(&c_tar[i], lt[i]);
        if (ls[i]) atomicAdd(&c_src[i], ls[i]);
    }
}

#define SCAN_TILE 1024

__global__ __launch_bounds__(256) void scan_part(
    const int* __restrict__ in, int* __restrict__ out, int* __restrict__ bsums, int n)
{
    __shared__ int lds[256];
    int t = threadIdx.x;
    int base = blockIdx.x * SCAN_TILE + t * 4;
    int v[4];
#pragma unroll
    for (int j = 0; j < 4; ++j) v[j] = (base + j < n) ? in[base + j] : 0;
    int s = v[0] + v[1] + v[2] + v[3];
    lds[t] = s;
    __syncthreads();
    for (int off = 1; off < 256; off <<= 1) {
        int x = (t >= off) ? lds[t - off] : 0;
        __syncthreads();
        lds[t] += x;
        __syncthreads();
    }
    int run = lds[t] - s;
#pragma unroll
    for (int j = 0; j < 4; ++j) {
        if (base + j < n) out[base + j] = run;
        run += v[j];
    }
    if (t == 255) bsums[blockIdx.x] = lds[255];
}

__global__ __launch_bounds__(256) void scan_sums(int* __restrict__ bsums, int nb)
{
    __shared__ int lds[256];
    int t = threadIdx.x;
    int v = (t < nb) ? bsums[t] : 0;
    lds[t] = v;
    __syncthreads();
    for (int off = 1; off < 256; off <<= 1) {
        int x = (t >= off) ? lds[t - off] : 0;
        __syncthreads();
        lds[t] += x;
        __syncthreads();
    }
    if (t < nb) bsums[t] = lds[t] - v;
}

__global__ __launch_bounds__(256) void add_off(
    int* __restrict__ rp, const int* __restrict__ bsums, int n, int total)
{
    int i = blockIdx.x * blockDim.x + threadIdx.x;
    if (i < n) rp[i] += bsums[i >> 10];
    if (i == 0) rp[n] = total;
}

__global__ __launch_bounds__(256) void init_tails(
    const int* __restrict__ off_t, int* __restrict__ tl_t,
    const int* __restrict__ off_s, int* __restrict__ tl_s)
{
    int i = blockIdx.x * blockDim.x + threadIdx.x;
    if (i < NBUCK) { tl_t[i] = off_t[i]; tl_s[i] = off_s[i]; }
}

// stage edges into coarse-bucket extents. One range-reservation atomic per
// (block, bucket); writes land grouped (~8 edges = 64 B per segment).
// rec = { row, (col<<15) | (bf16(val) bits 14..0) }
template <int SH>
__global__ __launch_bounds__(256) void csr_stage(
    const int* __restrict__ rows, const int* __restrict__ cols,
    const float* __restrict__ vals,
    int* __restrict__ tails, uint2* __restrict__ stag, int nnz)
{
    __shared__ int lh[NBUCK];     // per-bucket count in this chunk
    __shared__ int lbase[NBUCK];  // reserved global base
    int t = threadIdx.x;
    int s = blockIdx.x * CHUNK, e = min(s + CHUNK, nnz);
    for (int i = t; i < NBUCK; i += 256) lh[i] = 0;
    __syncthreads();
    for (int i = s + t; i < e; i += 256) atomicAdd(&lh[rows[i] >> SH], 1);
    __syncthreads();
    for (int i = t; i < NBUCK; i += 256) {
        int c = lh[i];
        lbase[i] = c ? atomicAdd(&tails[i], c) : 0;
        lh[i] = 0;   // reuse as intra-block tail
    }
    __syncthreads();
    for (int i = s + t; i < e; i += 256) {
        int r = rows[i];
        int b = r >> SH;
        int pos = lbase[b] + atomicAdd(&lh[b], 1);
        uint uv = __float_as_uint(vals[i]);
        uv += 0x7fffu + ((uv >> 16) & 1u);          // RNE to bf16 (val>=0)
        stag[pos] = make_uint2((uint)r, ((uint)cols[i] << 15) | ((uv >> 16) & 0x7fffu));
    }
}

// one block per bucket: build rp (exact row offsets) and write packed CSR
// sequentially within the bucket's ~8 KB extent, records cached in LDS.
template <int SH>
__global__ __launch_bounds__(256) void csr_finalize(
    const uint2* __restrict__ stag, const int* __restrict__ off,
    int* __restrict__ rp, uint* __restrict__ ep, int nrows, int nnz)
{
    __shared__ uint2 recs[4096];
    __shared__ int lhist[1 << SH];
    __shared__ int lbase[(1 << SH) + 1];
    const int RPB = 1 << SH;
    int b = blockIdx.x, t = threadIdx.x;
    int base = off[b];
    int n = off[b + 1] - base;
    int r0 = b << SH;

    for (int i = t; i < RPB; i += 256) lhist[i] = 0;
    __syncthreads();

    if (n <= 4096) {
        for (int i = t; i < n; i += 256) {
            uint2 rec = stag[base + i];
            recs[i] = rec;
            atomicAdd(&lhist[(int)rec.x - r0], 1);
        }
        __syncthreads();
        if (t == 0) {
            int run = 0;
            for (int i = 0; i < RPB; ++i) { lbase[i] = run; run += lhist[i]; }
            lbase[RPB] = run;
        }
        __syncthreads();
        for (int i = t; i < RPB; i += 256) {
            int rg = r0 + i;
            if (rg < nrows) rp[rg] = base + lbase[i];
        }
        if (b == 0 && t == 0) rp[nrows] = nnz;
        for (int i = t; i < RPB; i += 256) lhist[i] = 0;
        __syncthreads();
        for (int i = t; i < n; i += 256) {
            uint2 rec = recs[i];
            int rl = (int)rec.x - r0;
            int slot = lbase[rl] + atomicAdd(&lhist[rl], 1);
            ep[base + slot] = rec.y;
        }
    } else {
        // statistically unreachable (buckets ~2046 +/- 45); correct fallback
        for (int i = t; i < n; i += 256)
            atomicAdd(&lhist[(int)stag[base + i].x - r0], 1);
        __syncthreads();
        if (t == 0) {
            int run = 0;
            for (int i = 0; i < RPB; ++i) { lbase[i] = run; run += lhist[i]; }
            lbase[RPB] = run;
        }
        __syncthreads();
        for (int i = t; i < RPB; i += 256) {
            int rg = r0 + i;
            if (rg < nrows) rp[rg] = base + lbase[i];
        }
        if (b == 0 && t == 0) rp[nrows] = nnz;
        for (int i = t; i < RPB; i += 256) lhist[i] = 0;
        __syncthreads();
        for (int i = t; i < n; i += 256) {
            uint2 rec = stag[base + i];
            int rl = (int)rec.x - r0;
            int slot = lbase[rl] + atomicAdd(&lhist[rl], 1);
            ep[base + slot] = rec.y;
        }
    }
}

// ---------- gather SpMM cores (full-D, batched depth-8, packed 4-B edges) ----------
// row is wave-uniform (readfirstlane) -> edge loads are scalar broadcasts.
// decode: col = u >> 15, val = f32 from bf16 bits (u & 0x7fff) << 16 (val >= 0).
// pad u = 0 -> col 0, val +0.0 (exact no-op) keeps full load depth on tails.
#define GCH 8

__device__ __forceinline__ float4 gather_h(
    const int* __restrict__ rp, const uint* __restrict__ ep,
    const uint2* __restrict__ dh, int row, int lane)
{
    int s = rp[row], e = rp[row + 1];
    float4 acc = {0.f, 0.f, 0.f, 0.f};
    for (int k = s; k < e; k += GCH) {
        uint ev[GCH];
#pragma unroll
        for (int j = 0; j < GCH; ++j)
            ev[j] = (k + j < e) ? ep[k + j] : 0u;
        uint2 x[GCH];
#pragma unroll
        for (int j = 0; j < GCH; ++j)
            x[j] = dh[(size_t)(ev[j] >> 15) * (DIM / 4) + lane];
#pragma unroll
        for (int j = 0; j < GCH; ++j) {
            float vv = __uint_as_float((ev[j] & 0x7fffu) << 16);
            acc.x += vv * __uint_as_float(x[j].x << 16);
            acc.y += vv * __uint_as_float(x[j].x & 0xffff0000u);
            acc.z += vv * __uint_as_float(x[j].y << 16);
            acc.w += vv * __uint_as_float(x[j].y & 0xffff0000u);
        }
    }
    return acc;
}

__device__ __forceinline__ float4 gather_f(
    const int* __restrict__ rp, const uint* __restrict__ ep,
    const float4* __restrict__ d4, int row, int lane)
{
    int s = rp[row], e = rp[row + 1];
    float4 acc = {0.f, 0.f, 0.f, 0.f};
    for (int k = s; k < e; k += GCH) {
        uint ev[GCH];
#pragma unroll
        for (int j = 0; j < GCH; ++j)
            ev[j] = (k + j < e) ? ep[k + j] : 0u;
        float4 x[GCH];
#pragma unroll
        for (int j = 0; j < GCH; ++j)
            x[j] = d4[(size_t)(ev[j] >> 15) * (DIM / 4) + lane];
#pragma unroll
        for (int j = 0; j < GCH; ++j) {
            float vv = __uint_as_float((ev[j] & 0x7fffu) << 16);
            acc.x += vv * x[j].x;
            acc.y += vv * x[j].y;
            acc.z += vv * x[j].z;
            acc.w += vv * x[j].w;
        }
    }
    return acc;
}

// hyperedge-side SpMM -> bf16 out. BF16D: dense is bf16 (else f32).
template <bool BF16D>
__global__ __launch_bounds__(256) void spmm_to_h(
    const int* __restrict__ rp, const uint* __restrict__ ep,
    const void* __restrict__ dense, uint2* __restrict__ out_h, int nrows)
{
    int wid  = (blockIdx.x * blockDim.x + threadIdx.x) >> 6;
    int lane = threadIdx.x & 63;
    if (wid >= nrows) return;
    int row = __builtin_amdgcn_readfirstlane(wid);
    float4 a = BF16D ? gather_h(rp, ep, (const uint2*)dense, row, lane)
                     : gather_f(rp, ep, (const float4*)dense, row, lane);
    out_h[(size_t)row * (DIM / 4) + lane] = make_uint2(pack_bf16(a.x, a.y), pack_bf16(a.z, a.w));
}

// poi-side SpMM + layer-1 epilogue -> embs1 (bf16).
template <bool PH>
__global__ __launch_bounds__(256) void spmm_epi1(
    const int* __restrict__ rp, const uint* __restrict__ ep,
    const uint2* __restrict__ msg_h,
    const uint2* __restrict__ pois_h, const float4* __restrict__ pois_f,
    const float4* __restrict__ d1, const float4* __restrict__ d2,
    uint2* __restrict__ out_h, int nrows)
{
    int wid  = (blockIdx.x * blockDim.x + threadIdx.x) >> 6;
    int lane = threadIdx.x & 63;
    if (wid >= nrows) return;
    int row = __builtin_amdgcn_readfirstlane(wid);
    size_t idx = (size_t)row * (DIM / 4) + lane;
    float4 a = d1[idx], b = d2[idx];
    float4 p = PH ? unpack_h(pois_h[idx]) : pois_f[idx];
    float4 m = gather_h(rp, ep, msg_h, row, lane);
    float4 r;
    r.x = (fmaxf(m.x, 0.f) * a.x + p.x) * b.x;
    r.y = (fmaxf(m.y, 0.f) * a.y + p.y) * b.y;
    r.z = (fmaxf(m.z, 0.f) * a.z + p.z) * b.z;
    r.w = (fmaxf(m.w, 0.f) * a.w + p.w) * b.w;
    out_h[idx] = make_uint2(pack_bf16(r.x, r.y), pack_bf16(r.z, r.w));
}

// poi-side SpMM + layer-2 epilogue + softmax-weighted combine -> f32 out.
template <bool PH>
__global__ __launch_bounds__(256) void spmm_final(
    const int* __restrict__ rp, const uint* __restrict__ ep,
    const uint2* __restrict__ msg_h,
    const uint2* __restrict__ pois_h, const float4* __restrict__ pois_f,
    const uint2* __restrict__ embs1_h,
    const float4* __restrict__ d1, const float4* __restrict__ d2,
    const float* __restrict__ attn, float4* __restrict__ out, int nrows)
{
    int wid  = (blockIdx.x * blockDim.x + threadIdx.x) >> 6;
    int lane = threadIdx.x & 63;
    if (wid >= nrows) return;
    int row = __builtin_amdgcn_readfirstlane(wid);

    float a0 = attn[0], a1 = attn[1], a2 = attn[2];
    float mx = fmaxf(a0, fmaxf(a1, a2));
    float e0 = __expf(a0 - mx), e1 = __expf(a1 - mx), e2 = __expf(a2 - mx);
    float inv = 1.f / (e0 + e1 + e2);
    float w0 = e0 * inv, w1 = e1 * inv, w2 = e2 * inv;

    size_t idx = (size_t)row * (DIM / 4) + lane;
    float4 a = d1[idx], b = d2[idx];
    float4 p0 = PH ? unpack_h(pois_h[idx]) : pois_f[idx];
    float4 p1 = unpack_h(embs1_h[idx]);
    float4 m = gather_h(rp, ep, msg_h, row, lane);
    float4 r;
    r.x = w0 * p0.x + w1 * p1.x + w2 * ((fmaxf(m.x, 0.f) * a.x + p1.x) * b.x);
    r.y = w0 * p0.y + w1 * p1.y + w2 * ((fmaxf(m.y, 0.f) * a.y + p1.y) * b.y);
    r.z = w0 * p0.z + w1 * p1.z + w2 * ((fmaxf(m.z, 0.f) * a.z + p1.z) * b.z);
    r.w = w0 * p0.w + w1 * p1.w + w2 * ((fmaxf(m.w, 0.f) * a.w + p1.w) * b.w);
    out[idx] = r;
}

// ---------- launch ----------
extern "C" void kernel_launch(void* const* d_in, const int* in_sizes, int n_in,
                              void* d_out, int out_size, void* d_ws, size_t ws_size,
                              hipStream_t stream)
{
    const float* pois     = (const float*)d_in[0];
    const float* tar_vals = (const float*)d_in[1];
    const float* src_vals = (const float*)d_in[2];
    const float* attn     = (const float*)d_in[3];
    const float* drop1    = (const float*)d_in[4];
    const float* drop2    = (const float*)d_in[5];
    const int*   tar_rows = (const int*)d_in[6];
    const int*   tar_cols = (const int*)d_in[7];
    const int*   src_rows = (const int*)d_in[8];
    const int*   src_cols = (const int*)d_in[9];
    float* out = (float*)d_out;

    const size_t ptn = (size_t)NPOIS * DIM;

    // workspace layout (packed 4-B edges; pois_h needs only 141.4 MB total)
    char* p = (char*)d_ws;
    uint* ep_tar   = (uint*)p;              p += (size_t)NNZE * 4;            // 6.4 MB
    uint* ep_src   = (uint*)p;              p += (size_t)NNZE * 4;            // 6.4 MB
    int*  rp_tar   = (int*)p;               p += 200064;                      // NHYP+1
    int*  rp_src   = (int*)p;               p += 400064;                      // NPOIS+1
    int*  misc     = (int*)p;               p += 32768;                       // counters
    uint2* msg_h   = (uint2*)p;             p += (size_t)NHYP * DIM * 2;      // 25.6 MB
    uint2* embs1_h = (uint2*)p;             p += (size_t)NPOIS * DIM * 2;     // 51.2 MB
    size_t base_need = (size_t)(p - (char*)d_ws);
    uint2* pois_h  = (uint2*)p;                                               // +51.2 MB
    bool full = ws_size >= base_need + ptn * 2;

    // misc carve-up (ints)
    int* cntc_tar = misc;                 // 782
    int* off_tar  = cntc_tar + NBUCK;     // 783
    int* tl_tar   = off_tar + NBUCK + 1;  // 782
    int* cntc_src = tl_tar + NBUCK;       // 782
    int* off_src  = cntc_src + NBUCK;     // 783
    int* tl_src   = off_src + NBUCK + 1;  // 782
    int* bsums    = tl_src + NBUCK;       // 16

    // staging overlays msg_h (CSR build completes before msg_h is written):
    // 2 * NNZE * 8 B = 25.6 MB = sizeof(msg_h) exactly
    uint2* stag_tar = (uint2*)msg_h;
    uint2* stag_src = stag_tar + NNZE;

    const int BLK = 256;

    // optional f32->bf16 pois copy
    if (full)
        to_h_kernel<<<(int)(ptn / 4 + BLK - 1) / BLK, BLK, 0, stream>>>(
            (const float4*)pois, pois_h, (int)(ptn / 4));

    // ---- CSR build v2 ----
    hipMemsetAsync(misc, 0, 32768, stream);
    hist_coarse<<<256, BLK, 0, stream>>>(tar_rows, src_rows, cntc_tar, cntc_src, NNZE);

    scan_part<<<1, BLK, 0, stream>>>(cntc_tar, off_tar, bsums, NBUCK);
    scan_sums<<<1, BLK, 0, stream>>>(bsums, 1);
    add_off<<<(NBUCK + BLK - 1) / BLK, BLK, 0, stream>>>(off_tar, bsums, NBUCK, NNZE);

    scan_part<<<1, BLK, 0, stream>>>(cntc_src, off_src, bsums, NBUCK);
    scan_sums<<<1, BLK, 0, stream>>>(bsums, 1);
    add_off<<<(NBUCK + BLK - 1) / BLK, BLK, 0, stream>>>(off_src, bsums, NBUCK, NNZE);

    init_tails<<<(NBUCK + BLK - 1) / BLK, BLK, 0, stream>>>(off_tar, tl_tar, off_src, tl_src);

    csr_stage<SH_TAR><<<256, BLK, 0, stream>>>(tar_rows, tar_cols, tar_vals, tl_tar, stag_tar, NNZE);
    csr_stage<SH_SRC><<<256, BLK, 0, stream>>>(src_rows, src_cols, src_vals, tl_src, stag_src, NNZE);

    csr_finalize<SH_TAR><<<NBUCK, BLK, 0, stream>>>(stag_tar, off_tar, rp_tar, ep_tar, NHYP, NNZE);
    csr_finalize<SH_SRC><<<NBUCK, BLK, 0, stream>>>(stag_src, off_src, rp_src, ep_src, NPOIS, NNZE);

    const int gb_hyp = NHYP / 4;   // 12500 blocks (4 waves each)
    const int gb_poi = NPOIS / 4;  // 25000 blocks

    // ---- layer 1 ----
    if (full)
        spmm_to_h<true><<<gb_hyp, BLK, 0, stream>>>(rp_tar, ep_tar, pois_h, msg_h, NHYP);
    else
        spmm_to_h<false><<<gb_hyp, BLK, 0, stream>>>(rp_tar, ep_tar, pois, msg_h, NHYP);

    if (full)
        spmm_epi1<true><<<gb_poi, BLK, 0, stream>>>(
            rp_src, ep_src, msg_h, pois_h, (const float4*)pois,
            (const float4*)drop1, (const float4*)drop2, embs1_h, NPOIS);
    else
        spmm_epi1<false><<<gb_poi, BLK, 0, stream>>>(
            rp_src, ep_src, msg_h, pois_h, (const float4*)pois,
            (const float4*)drop1, (const float4*)drop2, embs1_h, NPOIS);

    // ---- layer 2 ----
    spmm_to_h<true><<<gb_hyp, BLK, 0, stream>>>(rp_tar, ep_tar, embs1_h, msg_h, NHYP);

    if (full)
        spmm_final<true><<<gb_poi, BLK, 0, stream>>>(
            rp_src, ep_src, msg_h, pois_h, (const float4*)pois, embs1_h,
            (const float4*)(drop1 + ptn), (const float4*)(drop2 + ptn),
            attn, (float4*)out, NPOIS);
    else
        spmm_final<false><<<gb_poi, BLK, 0, stream>>>(
            rp_src, ep_src, msg_h, pois_h, (const float4*)pois, embs1_h,
            (const float4*)(drop1 + ptn), (const float4*)(drop2 + ptn),
            attn, (float4*)out, NPOIS);
}

// Round 6
// 1184.461 us; speedup vs baseline: 1.2318x; 1.0018x over previous
//
#include <hip/hip_runtime.h>

#define NPOIS 100000
#define NHYP  50000
#define NNZE  1600000
#define DIM   256

// coarse bucket shifts: 782 buckets for both matrices
#define SH_TAR 6    // 64 rows/bucket, ceil(50000/64)  = 782
#define SH_SRC 7    // 128 rows/bucket, ceil(100000/128) = 782
#define NBUCK 782
#define CHUNK 6250  // 256 blocks * 6250 = 1,600,000 = NNZE exactly

typedef unsigned int uint;

// exact f32 value of the reference's dropout scale 1/(1-0.3)
#define DROP_C ((float)(1.0 / (1.0 - 0.3)))

// ---------- bf16 helpers (RNE) ----------
__device__ __forceinline__ uint pack_bf16(float a, float b) {
    uint ua = __float_as_uint(a); ua += 0x7fffu + ((ua >> 16) & 1u);
    uint ub = __float_as_uint(b); ub += 0x7fffu + ((ub >> 16) & 1u);
    return (ua >> 16) | (ub & 0xffff0000u);
}
__device__ __forceinline__ float4 unpack_h(uint2 u) {
    return make_float4(__uint_as_float(u.x << 16), __uint_as_float(u.x & 0xffff0000u),
                       __uint_as_float(u.y << 16), __uint_as_float(u.y & 0xffff0000u));
}

// f32 [n4 float4] -> bf16 [n4 uint2]
__global__ __launch_bounds__(256) void to_h_kernel(
    const float4* __restrict__ in, uint2* __restrict__ out, int n4)
{
    int stride = gridDim.x * blockDim.x;
    for (int i = blockIdx.x * blockDim.x + threadIdx.x; i < n4; i += stride) {
        float4 x = in[i];
        out[i] = make_uint2(pack_bf16(x.x, x.y), pack_bf16(x.z, x.w));
    }
}

// drop masks (values in {0, DROP_C}) -> 1 bit per element.
// word w covers elements [32w, 32w+32) of the flattened (L, NPOIS, DIM)
// array; bit j <-> element 32w+j. (decode path verified in round 1)
__global__ __launch_bounds__(256) void drop_bits_kernel(
    const float4* __restrict__ d1, const float4* __restrict__ d2,
    uint* __restrict__ o1, uint* __restrict__ o2, int nw)
{
    int t = blockIdx.x * blockDim.x + threadIdx.x;
    if (t >= 2 * nw) return;
    const float4* src = (t < nw) ? d1 : d2;
    uint* dst = (t < nw) ? o1 : o2;
    int w = (t < nw) ? t : t - nw;
    uint m = 0;
#pragma unroll
    for (int q = 0; q < 8; ++q) {
        float4 v = src[(size_t)w * 8 + q];
        m |= (v.x != 0.f ? 1u : 0u) << (4 * q);
        m |= (v.y != 0.f ? 2u : 0u) << (4 * q);
        m |= (v.z != 0.f ? 4u : 0u) << (4 * q);
        m |= (v.w != 0.f ? 8u : 0u) << (4 * q);
    }
    dst[w] = m;
}

// ---------- CSR build v2 (round-5 verified), launch-fused ----------

// coarse histogram, LDS-aggregated (both matrices in one pass)
__global__ __launch_bounds__(256) void hist_coarse(
    const int* __restrict__ tr, const int* __restrict__ sr,
    int* __restrict__ c_tar, int* __restrict__ c_src, int nnz)
{
    __shared__ int lt[NBUCK], ls[NBUCK];
    int t = threadIdx.x;
    int s = blockIdx.x * CHUNK, e = min(s + CHUNK, nnz);
    for (int i = t; i < NBUCK; i += 256) { lt[i] = 0; ls[i] = 0; }
    __syncthreads();
    for (int i = s + t; i < e; i += 256) {
        atomicAdd(&lt[tr[i] >> SH_TAR], 1);
        atomicAdd(&ls[sr[i] >> SH_SRC], 1);
    }
    __syncthreads();
    for (int i = t; i < NBUCK; i += 256) {
        if (lt[i]) atomicAdd(&c_tar[i], lt[i]);
        if (ls[i]) atomicAdd(&c_src[i], ls[i]);
    }
}

// one block: exclusive-scan both 782-entry coarse histograms, write offsets
// and tail counters. Replaces 6 scan launches + init_tails.
__global__ __launch_bounds__(256) void scan_offsets(
    const int* __restrict__ c_tar, const int* __restrict__ c_src,
    int* __restrict__ off_tar, int* __restrict__ tl_tar,
    int* __restrict__ off_src, int* __restrict__ tl_src)
{
    __shared__ int lds[256];
    int t = threadIdx.x;
    for (int sel = 0; sel < 2; ++sel) {
        const int* c = sel ? c_src : c_tar;
        int* off = sel ? off_src : off_tar;
        int* tl  = sel ? tl_src : tl_tar;
        int carry = 0;
        for (int base = 0; base < NBUCK; base += 256) {
            int i = base + t;
            int v = (i < NBUCK) ? c[i] : 0;
            lds[t] = v;
            __syncthreads();
            for (int o = 1; o < 256; o <<= 1) {
                int x = (t >= o) ? lds[t - o] : 0;
                __syncthreads();
                lds[t] += x;
                __syncthreads();
            }
            int excl = carry + lds[t] - v;
            if (i < NBUCK) { off[i] = excl; tl[i] = excl; }
            carry += lds[255];
            __syncthreads();
        }
        if (t == 0) off[NBUCK] = carry;
        __syncthreads();
    }
}

// stage edges into coarse-bucket extents (both matrices; blocks 0..255 tar,
// 256..511 src). One range-reservation atomic per (block,bucket).
// rec = { row, (col<<15) | (bf16(val) bits 14..0) }
__global__ __launch_bounds__(256) void csr_stage(
    const int* __restrict__ tar_rows, const int* __restrict__ tar_cols,
    const float* __restrict__ tar_vals,
    const int* __restrict__ src_rows, const int* __restrict__ src_cols,
    const float* __restrict__ src_vals,
    int* __restrict__ tl_tar, uint2* __restrict__ stag_tar,
    int* __restrict__ tl_src, uint2* __restrict__ stag_src, int nnz)
{
    __shared__ int lh[NBUCK];
    __shared__ int lbase[NBUCK];
    int t = threadIdx.x;
    bool is_src = blockIdx.x >= 256;
    int blk = is_src ? blockIdx.x - 256 : blockIdx.x;
    const int* rows = is_src ? src_rows : tar_rows;
    const int* cols = is_src ? src_cols : tar_cols;
    const float* vals = is_src ? src_vals : tar_vals;
    int* tails = is_src ? tl_src : tl_tar;
    uint2* stag = is_src ? stag_src : stag_tar;
    const int SH = is_src ? SH_SRC : SH_TAR;

    int s = blk * CHUNK, e = min(s + CHUNK, nnz);
    for (int i = t; i < NBUCK; i += 256) lh[i] = 0;
    __syncthreads();
    for (int i = s + t; i < e; i += 256) atomicAdd(&lh[rows[i] >> SH], 1);
    __syncthreads();
    for (int i = t; i < NBUCK; i += 256) {
        int c = lh[i];
        lbase[i] = c ? atomicAdd(&tails[i], c) : 0;
        lh[i] = 0;   // reuse as intra-block tail
    }
    __syncthreads();
    for (int i = s + t; i < e; i += 256) {
        int r = rows[i];
        int b = r >> SH;
        int pos = lbase[b] + atomicAdd(&lh[b], 1);
        uint uv = __float_as_uint(vals[i]);
        uv += 0x7fffu + ((uv >> 16) & 1u);          // RNE to bf16 (val>=0)
        stag[pos] = make_uint2((uint)r, ((uint)cols[i] << 15) | ((uv >> 16) & 0x7fffu));
    }
}

// one block per bucket (both matrices; blocks 0..781 tar, 782..1563 src):
// build rp and write packed CSR sequentially within the bucket extent.
__global__ __launch_bounds__(256) void csr_finalize(
    const uint2* __restrict__ stag_tar, const int* __restrict__ off_tar,
    int* __restrict__ rp_tar, uint* __restrict__ ep_tar,
    const uint2* __restrict__ stag_src, const int* __restrict__ off_src,
    int* __restrict__ rp_src, uint* __restrict__ ep_src, int nnz)
{
    __shared__ uint2 recs[4096];
    __shared__ int lhist[128];
    __shared__ int lbase[129];
    bool is_src = blockIdx.x >= NBUCK;
    int b = is_src ? blockIdx.x - NBUCK : blockIdx.x;
    const uint2* stag = is_src ? stag_src : stag_tar;
    const int* off = is_src ? off_src : off_tar;
    int* rp = is_src ? rp_src : rp_tar;
    uint* ep = is_src ? ep_src : ep_tar;
    const int SH = is_src ? SH_SRC : SH_TAR;
    const int RPB = 1 << SH;
    const int nrows = is_src ? NPOIS : NHYP;
    int t = threadIdx.x;
    int base = off[b];
    int n = off[b + 1] - base;
    int r0 = b << SH;

    for (int i = t; i < RPB; i += 256) lhist[i] = 0;
    __syncthreads();

    bool fit = (n <= 4096);
    for (int i = t; i < n; i += 256) {
        uint2 rec = stag[base + i];
        if (fit) recs[i] = rec;
        atomicAdd(&lhist[(int)rec.x - r0], 1);
    }
    __syncthreads();
    if (t == 0) {
        int run = 0;
        for (int i = 0; i < RPB; ++i) { lbase[i] = run; run += lhist[i]; }
        lbase[RPB] = run;
    }
    __syncthreads();
    for (int i = t; i < RPB; i += 256) {
        int rg = r0 + i;
        if (rg < nrows) rp[rg] = base + lbase[i];
    }
    if (b == 0 && t == 0) rp[nrows] = nnz;
    for (int i = t; i < RPB; i += 256) lhist[i] = 0;
    __syncthreads();
    for (int i = t; i < n; i += 256) {
        uint2 rec = fit ? recs[i] : stag[base + i];
        int rl = (int)rec.x - r0;
        int slot = lbase[rl] + atomicAdd(&lhist[rl], 1);
        ep[base + slot] = rec.y;
    }
}

// ---------- gather SpMM cores (full-D, batched depth-8, packed 4-B edges) ----------
// row is wave-uniform (readfirstlane) -> edge loads are scalar broadcasts.
// decode: col = u >> 15, val = f32 from bf16 bits (u & 0x7fff) << 16 (val >= 0).
// pad u = 0 -> col 0, val +0.0 (exact no-op) keeps full load depth on tails.
#define GCH 8

__device__ __forceinline__ float4 gather_h(
    const int* __restrict__ rp, const uint* __restrict__ ep,
    const uint2* __restrict__ dh, int row, int lane)
{
    int s = rp[row], e = rp[row + 1];
    float4 acc = {0.f, 0.f, 0.f, 0.f};
    for (int k = s; k < e; k += GCH) {
        uint ev[GCH];
#pragma unroll
        for (int j = 0; j < GCH; ++j)
            ev[j] = (k + j < e) ? ep[k + j] : 0u;
        uint2 x[GCH];
#pragma unroll
        for (int j = 0; j < GCH; ++j)
            x[j] = dh[(size_t)(ev[j] >> 15) * (DIM / 4) + lane];
#pragma unroll
        for (int j = 0; j < GCH; ++j) {
            float vv = __uint_as_float((ev[j] & 0x7fffu) << 16);
            acc.x += vv * __uint_as_float(x[j].x << 16);
            acc.y += vv * __uint_as_float(x[j].x & 0xffff0000u);
            acc.z += vv * __uint_as_float(x[j].y << 16);
            acc.w += vv * __uint_as_float(x[j].y & 0xffff0000u);
        }
    }
    return acc;
}

__device__ __forceinline__ float4 gather_f(
    const int* __restrict__ rp, const uint* __restrict__ ep,
    const float4* __restrict__ d4, int row, int lane)
{
    int s = rp[row], e = rp[row + 1];
    float4 acc = {0.f, 0.f, 0.f, 0.f};
    for (int k = s; k < e; k += GCH) {
        uint ev[GCH];
#pragma unroll
        for (int j = 0; j < GCH; ++j)
            ev[j] = (k + j < e) ? ep[k + j] : 0u;
        float4 x[GCH];
#pragma unroll
        for (int j = 0; j < GCH; ++j)
            x[j] = d4[(size_t)(ev[j] >> 15) * (DIM / 4) + lane];
#pragma unroll
        for (int j = 0; j < GCH; ++j) {
            float vv = __uint_as_float((ev[j] & 0x7fffu) << 16);
            acc.x += vv * x[j].x;
            acc.y += vv * x[j].y;
            acc.z += vv * x[j].z;
            acc.w += vv * x[j].w;
        }
    }
    return acc;
}

// drop-mask fetch for full-D lanes: lane covers dims [4*lane, 4*lane+4);
// word = row*8 + (lane>>3), bits (lane&7)*4 .. +3
__device__ __forceinline__ float4 drop4(const uint* __restrict__ bm, int row, int lane)
{
    uint m = bm[(size_t)row * 8 + (lane >> 3)] >> ((lane & 7) * 4);
    return make_float4((m & 1u) ? DROP_C : 0.f, (m & 2u) ? DROP_C : 0.f,
                       (m & 4u) ? DROP_C : 0.f, (m & 8u) ? DROP_C : 0.f);
}

// hyperedge-side SpMM -> bf16 out. BF16D: dense is bf16 (else f32).
template <bool BF16D>
__global__ __launch_bounds__(256) void spmm_to_h(
    const int* __restrict__ rp, const uint* __restrict__ ep,
    const void* __restrict__ dense, uint2* __restrict__ out_h, int nrows)
{
    int wid  = (blockIdx.x * blockDim.x + threadIdx.x) >> 6;
    int lane = threadIdx.x & 63;
    if (wid >= nrows) return;
    int row = __builtin_amdgcn_readfirstlane(wid);
    float4 a = BF16D ? gather_h(rp, ep, (const uint2*)dense, row, lane)
                     : gather_f(rp, ep, (const float4*)dense, row, lane);
    out_h[(size_t)row * (DIM / 4) + lane] = make_uint2(pack_bf16(a.x, a.y), pack_bf16(a.z, a.w));
}

// poi-side SpMM + layer-1 epilogue -> embs1 (bf16).
template <bool PH, bool BITS>
__global__ __launch_bounds__(256) void spmm_epi1(
    const int* __restrict__ rp, const uint* __restrict__ ep,
    const uint2* __restrict__ msg_h,
    const uint2* __restrict__ pois_h, const float4* __restrict__ pois_f,
    const float4* __restrict__ d1, const float4* __restrict__ d2,
    const uint* __restrict__ bm1, const uint* __restrict__ bm2,
    uint2* __restrict__ out_h, int nrows)
{
    int wid  = (blockIdx.x * blockDim.x + threadIdx.x) >> 6;
    int lane = threadIdx.x & 63;
    if (wid >= nrows) return;
    int row = __builtin_amdgcn_readfirstlane(wid);
    size_t idx = (size_t)row * (DIM / 4) + lane;
    float4 a, b;
    if (BITS) { a = drop4(bm1, row, lane); b = drop4(bm2, row, lane); }
    else      { a = d1[idx]; b = d2[idx]; }
    float4 p = PH ? unpack_h(pois_h[idx]) : pois_f[idx];
    float4 m = gather_h(rp, ep, msg_h, row, lane);
    float4 r;
    r.x = (fmaxf(m.x, 0.f) * a.x + p.x) * b.x;
    r.y = (fmaxf(m.y, 0.f) * a.y + p.y) * b.y;
    r.z = (fmaxf(m.z, 0.f) * a.z + p.z) * b.z;
    r.w = (fmaxf(m.w, 0.f) * a.w + p.w) * b.w;
    out_h[idx] = make_uint2(pack_bf16(r.x, r.y), pack_bf16(r.z, r.w));
}

// poi-side SpMM + layer-2 epilogue + softmax-weighted combine -> f32 out.
template <bool PH, bool BITS>
__global__ __launch_bounds__(256) void spmm_final(
    const int* __restrict__ rp, const uint* __restrict__ ep,
    const uint2* __restrict__ msg_h,
    const uint2* __restrict__ pois_h, const float4* __restrict__ pois_f,
    const uint2* __restrict__ embs1_h,
    const float4* __restrict__ d1, const float4* __restrict__ d2,
    const uint* __restrict__ bm1, const uint* __restrict__ bm2,
    const float* __restrict__ attn, float4* __restrict__ out, int nrows)
{
    int wid  = (blockIdx.x * blockDim.x + threadIdx.x) >> 6;
    int lane = threadIdx.x & 63;
    if (wid >= nrows) return;
    int row = __builtin_amdgcn_readfirstlane(wid);

    float a0 = attn[0], a1 = attn[1], a2 = attn[2];
    float mx = fmaxf(a0, fmaxf(a1, a2));
    float e0 = __expf(a0 - mx), e1 = __expf(a1 - mx), e2 = __expf(a2 - mx);
    float inv = 1.f / (e0 + e1 + e2);
    float w0 = e0 * inv, w1 = e1 * inv, w2 = e2 * inv;

    size_t idx = (size_t)row * (DIM / 4) + lane;
    float4 a, b;
    if (BITS) { a = drop4(bm1, row, lane); b = drop4(bm2, row, lane); }
    else      { a = d1[idx]; b = d2[idx]; }
    float4 p0 = PH ? unpack_h(pois_h[idx]) : pois_f[idx];
    float4 p1 = unpack_h(embs1_h[idx]);
    float4 m = gather_h(rp, ep, msg_h, row, lane);
    float4 r;
    r.x = w0 * p0.x + w1 * p1.x + w2 * ((fmaxf(m.x, 0.f) * a.x + p1.x) * b.x);
    r.y = w0 * p0.y + w1 * p1.y + w2 * ((fmaxf(m.y, 0.f) * a.y + p1.y) * b.y);
    r.z = w0 * p0.z + w1 * p1.z + w2 * ((fmaxf(m.z, 0.f) * a.z + p1.z) * b.z);
    r.w = w0 * p0.w + w1 * p1.w + w2 * ((fmaxf(m.w, 0.f) * a.w + p1.w) * b.w);
    out[idx] = r;
}

// ---------- launch ----------
extern "C" void kernel_launch(void* const* d_in, const int* in_sizes, int n_in,
                              void* d_out, int out_size, void* d_ws, size_t ws_size,
                              hipStream_t stream)
{
    const float* pois     = (const float*)d_in[0];
    const float* tar_vals = (const float*)d_in[1];
    const float* src_vals = (const float*)d_in[2];
    const float* attn     = (const float*)d_in[3];
    const float* drop1    = (const float*)d_in[4];
    const float* drop2    = (const float*)d_in[5];
    const int*   tar_rows = (const int*)d_in[6];
    const int*   tar_cols = (const int*)d_in[7];
    const int*   src_rows = (const int*)d_in[8];
    const int*   src_cols = (const int*)d_in[9];
    float* out = (float*)d_out;

    const size_t ptn = (size_t)NPOIS * DIM;

    // workspace layout: base 90.2 MB + bits 12.8 + pois_h 51.2 = 154.2 MB
    // (identical total to the round-0 layout that was measured to fit).
    char* p = (char*)d_ws;
    uint* ep_tar   = (uint*)p;              p += (size_t)NNZE * 4;            // 6.4 MB
    uint* ep_src   = (uint*)p;              p += (size_t)NNZE * 4;            // 6.4 MB
    int*  rp_tar   = (int*)p;               p += 200064;                      // NHYP+1
    int*  rp_src   = (int*)p;               p += 400064;                      // NPOIS+1
    int*  misc     = (int*)p;               p += 32768;                       // counters
    uint2* msg_h   = (uint2*)p;             p += (size_t)NHYP * DIM * 2;      // 25.6 MB
    uint2* embs1_h = (uint2*)p;             p += (size_t)NPOIS * DIM * 2;     // 51.2 MB

    const size_t bits_words = (size_t)2 * NPOIS * 8;   // per array (2 layers)
    uint* bits1 = (uint*)p;
    uint* bits2 = bits1 + bits_words;       p += 2 * bits_words * 4;          // 12.8 MB
    size_t bits_need = (size_t)(p - (char*)d_ws);
    bool have_bits = ws_size >= bits_need;

    uint2* pois_h  = (uint2*)p;                                               // +51.2 MB
    bool full = ws_size >= bits_need + ptn * 2;

    // misc carve-up (ints)
    int* cntc_tar = misc;                 // 782
    int* off_tar  = cntc_tar + NBUCK;     // 783
    int* tl_tar   = off_tar + NBUCK + 1;  // 782
    int* cntc_src = tl_tar + NBUCK;       // 782
    int* off_src  = cntc_src + NBUCK;     // 783
    int* tl_src   = off_src + NBUCK + 1;  // 782

    // staging overlays msg_h (CSR build completes before msg_h is written)
    uint2* stag_tar = (uint2*)msg_h;
    uint2* stag_src = stag_tar + NNZE;

    const int BLK = 256;

    // optional f32->bf16 pois copy
    if (full)
        to_h_kernel<<<(int)(ptn / 4 + BLK - 1) / BLK, BLK, 0, stream>>>(
            (const float4*)pois, pois_h, (int)(ptn / 4));

    // drop masks -> bits (both layers of both arrays in one pass)
    if (have_bits) {
        int nw = (int)(2 * ptn / 32);
        drop_bits_kernel<<<(2 * nw + BLK - 1) / BLK, BLK, 0, stream>>>(
            (const float4*)drop1, (const float4*)drop2, bits1, bits2, nw);
    }

    // ---- CSR build v2 (fused launches) ----
    hipMemsetAsync(misc, 0, 32768, stream);
    hist_coarse<<<256, BLK, 0, stream>>>(tar_rows, src_rows, cntc_tar, cntc_src, NNZE);
    scan_offsets<<<1, BLK, 0, stream>>>(cntc_tar, cntc_src, off_tar, tl_tar, off_src, tl_src);
    csr_stage<<<512, BLK, 0, stream>>>(
        tar_rows, tar_cols, tar_vals, src_rows, src_cols, src_vals,
        tl_tar, stag_tar, tl_src, stag_src, NNZE);
    csr_finalize<<<2 * NBUCK, BLK, 0, stream>>>(
        stag_tar, off_tar, rp_tar, ep_tar,
        stag_src, off_src, rp_src, ep_src, NNZE);

    const int gb_hyp = NHYP / 4;   // 12500 blocks (4 waves each)
    const int gb_poi = NPOIS / 4;  // 25000 blocks

    const float4* d1_l0 = (const float4*)drop1;
    const float4* d2_l0 = (const float4*)drop2;
    const float4* d1_l1 = (const float4*)(drop1 + ptn);
    const float4* d2_l1 = (const float4*)(drop2 + ptn);
    const uint* b1_l0 = bits1;
    const uint* b2_l0 = bits2;
    const uint* b1_l1 = bits1 + (size_t)NPOIS * 8;
    const uint* b2_l1 = bits2 + (size_t)NPOIS * 8;

    // ---- layer 1 ----
    if (full)
        spmm_to_h<true><<<gb_hyp, BLK, 0, stream>>>(rp_tar, ep_tar, pois_h, msg_h, NHYP);
    else
        spmm_to_h<false><<<gb_hyp, BLK, 0, stream>>>(rp_tar, ep_tar, pois, msg_h, NHYP);

    if (full && have_bits)
        spmm_epi1<true, true><<<gb_poi, BLK, 0, stream>>>(
            rp_src, ep_src, msg_h, pois_h, (const float4*)pois,
            d1_l0, d2_l0, b1_l0, b2_l0, embs1_h, NPOIS);
    else if (full)
        spmm_epi1<true, false><<<gb_poi, BLK, 0, stream>>>(
            rp_src, ep_src, msg_h, pois_h, (const float4*)pois,
            d1_l0, d2_l0, b1_l0, b2_l0, embs1_h, NPOIS);
    else if (have_bits)
        spmm_epi1<false, true><<<gb_poi, BLK, 0, stream>>>(
            rp_src, ep_src, msg_h, pois_h, (const float4*)pois,
            d1_l0, d2_l0, b1_l0, b2_l0, embs1_h, NPOIS);
    else
        spmm_epi1<false, false><<<gb_poi, BLK, 0, stream>>>(
            rp_src, ep_src, msg_h, pois_h, (const float4*)pois,
            d1_l0, d2_l0, b1_l0, b2_l0, embs1_h, NPOIS);

    // ---- layer 2 ----
    spmm_to_h<true><<<gb_hyp, BLK, 0, stream>>>(rp_tar, ep_tar, embs1_h, msg_h, NHYP);

    if (full && have_bits)
        spmm_final<true, true><<<gb_poi, BLK, 0, stream>>>(
            rp_src, ep_src, msg_h, pois_h, (const float4*)pois, embs1_h,
            d1_l1, d2_l1, b1_l1, b2_l1, attn, (float4*)out, NPOIS);
    else if (full)
        spmm_final<true, false><<<gb_poi, BLK, 0, stream>>>(
            rp_src, ep_src, msg_h, pois_h, (const float4*)pois, embs1_h,
            d1_l1, d2_l1, b1_l1, b2_l1, attn, (float4*)out, NPOIS);
    else if (have_bits)
        spmm_final<false, true><<<gb_poi, BLK, 0, stream>>>(
            rp_src, ep_src, msg_h, pois_h, (const float4*)pois, embs1_h,
            d1_l1, d2_l1, b1_l1, b2_l1, attn, (float4*)out, NPOIS);
    else
        spmm_final<false, false><<<gb_poi, BLK, 0, stream>>>(
            rp_src, ep_src, msg_h, pois_h, (const float4*)pois, embs1_h,
            d1_l1, d2_l1, b1_l1, b2_l1, attn, (float4*)out, NPOIS);
}